// Round 6
// baseline (178.676 us; speedup 1.0000x reference)
//
#include <hip/hip_runtime.h>
#include <hip/hip_bf16.h>
#include <cstdint>
#include <cstddef>

#define NSRC 100000
#define NDST 50000
#define DOUT 128
#define KK2 256   // 2*D

typedef __attribute__((ext_vector_type(8))) short bf16x8;
typedef __attribute__((ext_vector_type(4))) float f32x4;

static __device__ __forceinline__ unsigned short f2bf(float f) {
    union { float f; uint32_t u; } v; v.f = f;
    uint32_t u = v.u;
    uint32_t r = u + 0x7FFFu + ((u >> 16) & 1u);   // round-to-nearest-even
    return (unsigned short)(r >> 16);
}
static __device__ __forceinline__ float bf_lo(uint32_t u) {
    union { uint32_t x; float f; } v; v.x = u << 16; return v.f;
}
static __device__ __forceinline__ float bf_hi(uint32_t u) {
    union { uint32_t x; float f; } v; v.x = u & 0xFFFF0000u; return v.f;
}

// ---------------- K1: prep — WT bf16 convert + zero counters ----------------
__global__ __launch_bounds__(256) void k_prep(const float* __restrict__ W,
                                              unsigned short* __restrict__ WT,
                                              int* __restrict__ cnt,
                                              int* __restrict__ cnt2) {
    int i = blockIdx.x * 256 + threadIdx.x;
    if (i < DOUT * KK2) {
        int n = i >> 8;    // output col
        int k = i & 255;   // k index
        WT[i] = f2bf(W[k * DOUT + n]);
    }
    if (i < NDST) { cnt[i] = 0; cnt2[i] = 0; }
}

// ---------------- K2: hdelta_bf16 = bf16(H_src - HBar_src), fused dst histogram ----------------
__global__ __launch_bounds__(256) void k_hd_hist(const float4* __restrict__ a,
                                                 const float4* __restrict__ b,
                                                 ushort4* __restrict__ o,
                                                 const int* __restrict__ dst,
                                                 int* __restrict__ cnt,
                                                 int E, int n4) {
    int i = blockIdx.x * 256 + threadIdx.x;
    if (i < E) atomicAdd(&cnt[dst[i]], 1);   // fire-and-forget, hides under streaming
    if (i < n4) {
        float4 x = a[i], y = b[i];
        ushort4 u;
        u.x = f2bf(x.x - y.x); u.y = f2bf(x.y - y.y);
        u.z = f2bf(x.z - y.z); u.w = f2bf(x.w - y.w);
        o[i] = u;
    }
}

// ---------------- K3a: per-block sums ----------------
__global__ __launch_bounds__(256) void k_scan1(const int* __restrict__ cnt,
                                               int* __restrict__ bsum, int n) {
    int i = blockIdx.x * 256 + threadIdx.x;
    int v = (i < n) ? cnt[i] : 0;
#pragma unroll
    for (int s = 1; s < 64; s <<= 1) v += __shfl_xor(v, s, 64);
    __shared__ int wsum[4];
    if ((threadIdx.x & 63) == 0) wsum[threadIdx.x >> 6] = v;
    __syncthreads();
    if (threadIdx.x == 0) bsum[blockIdx.x] = wsum[0] + wsum[1] + wsum[2] + wsum[3];
}

// ---------------- K3b: merged scan — each block derives its own base from bsum,
//                  then scans its 256 cnt values and writes off ----------------
__global__ __launch_bounds__(256) void k_scan23(const int* __restrict__ cnt,
                                                const int* __restrict__ bsum,
                                                int* __restrict__ off,
                                                int n, int nb, int E) {
    __shared__ int wsum[4], wex[4];
    __shared__ int base_s;
    int t = threadIdx.x;
    int lane = t & 63, w = t >> 6;

    // phase A: scan the (nb<=256) block sums; pick out exclusive value at blockIdx.x
    int bv = (t < nb) ? bsum[t] : 0;
    int x = bv;
#pragma unroll
    for (int s = 1; s < 64; s <<= 1) { int tt = __shfl_up(x, s, 64); if (lane >= s) x += tt; }
    if (lane == 63) wsum[w] = x;
    __syncthreads();
    if (t == 0) {
        int run = 0;
#pragma unroll
        for (int k = 0; k < 4; ++k) { wex[k] = run; run += wsum[k]; }
    }
    __syncthreads();
    if (t == (int)blockIdx.x) base_s = wex[w] + x - bv;   // exclusive sum of bsum[0..blockIdx)
    __syncthreads();
    int base = base_s;
    __syncthreads();   // protect wsum/wex reuse

    // phase B: scan this block's cnt slice
    int i = blockIdx.x * 256 + t;
    int v = (i < n) ? cnt[i] : 0;
    x = v;
#pragma unroll
    for (int s = 1; s < 64; s <<= 1) { int tt = __shfl_up(x, s, 64); if (lane >= s) x += tt; }
    if (lane == 63) wsum[w] = x;
    __syncthreads();
    if (t == 0) {
        int run = 0;
#pragma unroll
        for (int k = 0; k < 4; ++k) { wex[k] = run; run += wsum[k]; }
    }
    __syncthreads();
    if (i < n) off[i] = base + wex[w] + x - v;
    if (blockIdx.x == 0 && t == 0) off[n] = E;
}

// ---------------- K4: scatter src ids into dst-sorted buckets ----------------
__global__ void k_scatter(const int* __restrict__ src, const int* __restrict__ dst,
                          const int* __restrict__ off, int* __restrict__ cur,
                          int* __restrict__ idx, int E) {
    int e = blockIdx.x * blockDim.x + threadIdx.x;
    if (e < E) {
        int d = dst[e];
        int p = off[d] + atomicAdd(&cur[d], 1);
        idx[p] = src[e];
    }
}

// ---------------- K5: fused gather-mean-agg + GEMM + bias + relu ----------------
// block = 1024 thr = 16 waves, owns 16 dst rows; ONE ROW PER WAVE.
// phase 1: wave w gathers row r0+w. Lane-parallel idx prefetch (idx[c+lane],
//          one coalesced load = 64 edge ids), broadcast via __shfl; unroll-8
//          => 8 independent 256B row-gathers in flight per wave.
// phase 2: waves 0..3 compute the 16x128 output tile via MFMA (idle waves park).
// LDS row stride 264 shorts: b128 reads 2-way bank aliased (free).
__global__ __launch_bounds__(1024, 8) void k_fused(const uint32_t* __restrict__ hd,
                                                   const float2* __restrict__ Hd,
                                                   const float2* __restrict__ agg,
                                                   const int* __restrict__ off,
                                                   const int* __restrict__ idx,
                                                   const unsigned short* __restrict__ WT,
                                                   const float* __restrict__ bias,
                                                   float* __restrict__ out) {
    __shared__ __align__(16) unsigned short xt[16][264];
    int r0 = blockIdx.x * 16;
    int w = threadIdx.x >> 6, lane = threadIdx.x & 63;

    // ---- phase 1: gather + mean + agg -> LDS x-tile (wave w -> row r0+w) ----
    int r = r0 + w;
    int o0 = off[r], o1 = off[r + 1];
    float accx = 0.f, accy = 0.f;
    for (int c = o0; c < o1; c += 64) {
        int m = o1 - c; if (m > 64) m = 64;
        int myi = (lane < m) ? idx[c + lane] : 0;
        int jm = m & ~7;
        for (int j = 0; j < jm; j += 8) {
            int s0 = __shfl(myi, j + 0), s1 = __shfl(myi, j + 1);
            int s2 = __shfl(myi, j + 2), s3 = __shfl(myi, j + 3);
            int s4 = __shfl(myi, j + 4), s5 = __shfl(myi, j + 5);
            int s6 = __shfl(myi, j + 6), s7 = __shfl(myi, j + 7);
            uint32_t v0 = hd[(size_t)s0 * 64 + lane];
            uint32_t v1 = hd[(size_t)s1 * 64 + lane];
            uint32_t v2 = hd[(size_t)s2 * 64 + lane];
            uint32_t v3 = hd[(size_t)s3 * 64 + lane];
            uint32_t v4 = hd[(size_t)s4 * 64 + lane];
            uint32_t v5 = hd[(size_t)s5 * 64 + lane];
            uint32_t v6 = hd[(size_t)s6 * 64 + lane];
            uint32_t v7 = hd[(size_t)s7 * 64 + lane];
            accx += bf_lo(v0) + bf_lo(v1) + bf_lo(v2) + bf_lo(v3)
                  + bf_lo(v4) + bf_lo(v5) + bf_lo(v6) + bf_lo(v7);
            accy += bf_hi(v0) + bf_hi(v1) + bf_hi(v2) + bf_hi(v3)
                  + bf_hi(v4) + bf_hi(v5) + bf_hi(v6) + bf_hi(v7);
        }
        for (int j = jm; j < m; ++j) {
            int s = __shfl(myi, j);
            uint32_t v = hd[(size_t)s * 64 + lane];
            accx += bf_lo(v);
            accy += bf_hi(v);
        }
    }
    float inv = 1.0f / fmaxf((float)(o1 - o0), 1.0f);
    float2 g = agg[(size_t)r * 64 + lane];
    float2 h = Hd[(size_t)r * 64 + lane];
    *(ushort2*)&xt[w][2 * lane]       = make_ushort2(f2bf(h.x), f2bf(h.y));
    *(ushort2*)&xt[w][128 + 2 * lane] = make_ushort2(f2bf(g.x + accx * inv),
                                                     f2bf(g.y + accy * inv));
    __syncthreads();

    // ---- phase 2: 16x128 GEMM tile, K=256 (waves 0..3 only) ----
    if (w < 4) {
        int lr = lane & 15, lg = lane >> 4;
        const bf16x8* B0 = reinterpret_cast<const bf16x8*>(WT + (size_t)(w * 32 + lr) * KK2 + lg * 8);
        const bf16x8* B1 = reinterpret_cast<const bf16x8*>(WT + (size_t)(w * 32 + 16 + lr) * KK2 + lg * 8);

        f32x4 acc0 = {0.f, 0.f, 0.f, 0.f};
        f32x4 acc1 = {0.f, 0.f, 0.f, 0.f};
#pragma unroll
        for (int kk = 0; kk < 8; ++kk) {
            bf16x8 av = *reinterpret_cast<const bf16x8*>(&xt[lr][lg * 8 + kk * 32]);
            acc0 = __builtin_amdgcn_mfma_f32_16x16x32_bf16(av, B0[kk * 4], acc0, 0, 0, 0);
            acc1 = __builtin_amdgcn_mfma_f32_16x16x32_bf16(av, B1[kk * 4], acc1, 0, 0, 0);
        }

        int col0 = w * 32 + lr;
        int col1 = col0 + 16;
        float bi0 = bias[col0], bi1 = bias[col1];
        int rowb = r0 + lg * 4;
#pragma unroll
        for (int j = 0; j < 4; ++j) {
            float v0 = acc0[j] + bi0;
            float v1 = acc1[j] + bi1;
            out[(size_t)(rowb + j) * DOUT + col0] = v0 > 0.f ? v0 : 0.f;
            out[(size_t)(rowb + j) * DOUT + col1] = v1 > 0.f ? v1 : 0.f;
        }
    }
}

extern "C" void kernel_launch(void* const* d_in, const int* in_sizes, int n_in,
                              void* d_out, int out_size, void* d_ws, size_t ws_size,
                              hipStream_t stream) {
    const float* H_src    = (const float*)d_in[0];
    const float* H_dst    = (const float*)d_in[1];
    const float* HBar_src = (const float*)d_in[2];
    const float* agg      = (const float*)d_in[3];
    const float* W        = (const float*)d_in[4];
    const float* bias     = (const float*)d_in[5];
    const int*   src      = (const int*)d_in[6];
    const int*   dst      = (const int*)d_in[7];
    float* out = (float*)d_out;
    const int E = in_sizes[6];
    const int NB = (NDST + 255) / 256;   // 196

    // ws layout (byte offsets, 512-aligned):
    //   cnt    : 0         .. 200,000
    //   cnt2   : 200,192   .. 400,192
    //   off    : 400,384   .. 600,388   (NDST+1)
    //   bsum   : 600,576   .. 601,360   (196 i32)
    //   idx    : 602,624   .. 3,802,624 (E i32)
    //   WT     : 3,803,136 .. 3,868,672 (128*256 bf16)
    //   hd_bf  : 3,868,672 .. 29,468,672 (NSRC*128 bf16)
    char* ws = (char*)d_ws;
    int* cnt             = (int*)ws;
    int* cnt2            = (int*)(ws + 200192);
    int* off             = (int*)(ws + 400384);
    int* bsum            = (int*)(ws + 600576);
    int* idx_sorted      = (int*)(ws + 602624);
    unsigned short* WT   = (unsigned short*)(ws + 3803136);
    unsigned short* hdbf = (unsigned short*)(ws + 3868672);

    k_prep<<<NB, 256, 0, stream>>>(W, WT, cnt, cnt2);

    int n4 = NSRC * 32;
    k_hd_hist<<<(n4 + 255) / 256, 256, 0, stream>>>(
        (const float4*)H_src, (const float4*)HBar_src, (ushort4*)hdbf,
        dst, cnt, E, n4);

    k_scan1<<<NB, 256, 0, stream>>>(cnt, bsum, NDST);
    k_scan23<<<NB, 256, 0, stream>>>(cnt, bsum, off, NDST, NB, E);

    k_scatter<<<(E + 255) / 256, 256, 0, stream>>>(src, dst, off, cnt2, idx_sorted, E);

    k_fused<<<NDST / 16, 1024, 0, stream>>>(
        (const uint32_t*)hdbf, (const float2*)H_dst, (const float2*)agg,
        off, idx_sorted, WT, bias, out);
}